// Round 3
// baseline (559.301 us; speedup 1.0000x reference)
//
#include <hip/hip_runtime.h>
#include <float.h>
#include <math.h>

// Problem constants
#define D_REAL 2331   // 259 channels * 3*3 patch
#define D_PAD  2336   // bf16 matrix row length
#define DQ     2304   // fp8 matrix row length (resp dims only; 18*128)
#define N_REAL 7225   // 85*85 patches
#define NPI    7424   // 29*256 padded patch count (both i and j dims)
#define NTILES 29     // 256-wide output tiles per dim

typedef __attribute__((ext_vector_type(8))) short bf16x8_t;  // 8 bf16 = 4 VGPRs
typedef __attribute__((ext_vector_type(16))) float f32x16_t; // 32x32 MFMA C/D
typedef __attribute__((ext_vector_type(8))) int   v8i_t;     // MX A/B operand
typedef __attribute__((ext_vector_type(4))) int   v4i_t;

__device__ __forceinline__ unsigned short f2bf(float x) {
    union { float f; unsigned int u; } v; v.f = x;
    unsigned int r = v.u + 0x7FFFu + ((v.u >> 16) & 1u);   // RNE
    return (unsigned short)(r >> 16);
}
__device__ __forceinline__ float bflo(unsigned int u) {
    union { unsigned int x; float f; } v; v.x = u << 16; return v.f;
}
__device__ __forceinline__ float bfhi(unsigned int u) {
    union { unsigned int x; float f; } v; v.x = u & 0xFFFF0000u; return v.f;
}

#define GLOAD_LDS16(g, l) __builtin_amdgcn_global_load_lds( \
    (const __attribute__((address_space(1))) void*)(g),     \
    (__attribute__((address_space(3))) void*)(l), 16, 0, 0)

// ---------------------------------------------------------------------------
// Fused build: resp part -> bf16 Pb[n][0..2304) AND fp8 Pq[n][0..2304);
// map part -> bf16 Pb[n][2304..2336) only (50 * avgpool4 + zero pad).
__global__ __launch_bounds__(256) void build_all(
        const float* __restrict__ respS, const float* __restrict__ respI,
        const float* __restrict__ mapS,  const float* __restrict__ mapI,
        unsigned short* __restrict__ PbS, unsigned short* __restrict__ PbI,
        unsigned char* __restrict__ PqS, unsigned char* __restrict__ PqI) {
    const int mat = blockIdx.y;
    unsigned short* Pb = mat ? PbI : PbS;
    const int bx = blockIdx.x;
    if (bx < 6120) {
        const float* resp = mat ? respI : respS;
        unsigned char* Pq = mat ? PqI : PqS;
        __shared__ float slab[5 * 768];        // [cc][rr][col], 15 KB max
        const int u  = bx / 72;                // 0..84
        const int d0 = (bx - u * 72) * 32;     // 0..2272
        const int c0 = d0 / 9;
        const int cN = (d0 + 31) / 9 - c0 + 1; // <= 5
        const int total = cN * 768;
        for (int idx = threadIdx.x; idx < total; idx += 256) {
            int cc = idx / 768;
            int rem = idx - cc * 768;          // (row-3u)*256 + col
            slab[idx] = resp[(((size_t)(c0 + cc)) << 16) + ((size_t)(3 * u) << 8) + rem];
        }
        __syncthreads();
        const int dl16 = threadIdx.x & 15;     // d-pair index
        const int de = d0 + 2 * dl16, dq = de + 1;
        const int ce = de / 9, re = de - ce * 9, pe = re / 3, qe = re - pe * 3;
        const int co = dq / 9, ro = dq - co * 9, po = ro / 3, qo = ro - po * 3;
        const int base_e = (ce - c0) * 768 + pe * 256 + qe;
        const int base_o = (co - c0) * 768 + po * 256 + qo;
        const int v0 = threadIdx.x >> 4;       // 0..15
        for (int v = v0; v < 85; v += 16) {
            float x0 = slab[base_e + 3 * v];
            float x1 = slab[base_o + 3 * v];
            size_t row = (size_t)(u * 85 + v);
            *(unsigned int*)&Pb[row * D_PAD + de] =
                (unsigned int)f2bf(x0) | ((unsigned int)f2bf(x1) << 16);
            int pk = __builtin_amdgcn_cvt_pk_fp8_f32(x0, x1, 0, false);
            *(unsigned short*)&Pq[row * DQ + de] = (unsigned short)pk;
        }
    } else {
        const float* map = mat ? mapI : mapS;
        int t = (bx - 6120) * 256 + threadIdx.x;
        int n = t >> 5, dm = t & 31;
        if (n >= N_REAL) return;
        float val = 0.f;
        if (dm < 27) {
            int u = n / 85, v = n - u * 85;
            int ch = dm / 9, r9 = dm - ch * 9, p = r9 / 3, q = r9 - p * 3;
            const float* mp = map + ((size_t)ch << 20)
                                  + ((size_t)((3 * u + p) * 4) << 10)
                                  + (size_t)((3 * v + q) * 4);
            float s = 0.f;
            #pragma unroll
            for (int a = 0; a < 4; a++)
                #pragma unroll
                for (int b = 0; b < 4; b++) s += mp[a * 1024 + b];
            val = 3.125f * s;                  // 50 * (1/16)
        }
        Pb[(size_t)n * D_PAD + 2304 + dm] = f2bf(val);
    }
}

// ---------------------------------------------------------------------------
// sinv[n] = 1/||S[:,n]|| (bf16 matrix); also zeroes the loss accumulator.
__global__ __launch_bounds__(256) void col_norms(const unsigned short* __restrict__ Sb,
                                                 float* __restrict__ sinv,
                                                 double* __restrict__ accum) {
    if (blockIdx.x == 0 && threadIdx.x == 0) *accum = 0.0;
    int n = blockIdx.x * 4 + (threadIdx.x >> 6);
    int lane = threadIdx.x & 63;
    const uint4* sp = (const uint4*)(Sb + (size_t)n * D_PAD);
    float s = 0.f;
    for (int k = lane; k < D_PAD / 8; k += 64) {
        uint4 a = sp[k];
        float x0 = bflo(a.x), x1 = bfhi(a.x), x2 = bflo(a.y), x3 = bfhi(a.y);
        float x4 = bflo(a.z), x5 = bfhi(a.z), x6 = bflo(a.w), x7 = bfhi(a.w);
        s = fmaf(x0, x0, s); s = fmaf(x1, x1, s);
        s = fmaf(x2, x2, s); s = fmaf(x3, x3, s);
        s = fmaf(x4, x4, s); s = fmaf(x5, x5, s);
        s = fmaf(x6, x6, s); s = fmaf(x7, x7, s);
    }
    #pragma unroll
    for (int off = 32; off > 0; off >>= 1) s += __shfl_xor(s, off);
    if (lane == 0) sinv[n] = (n < N_REAL) ? rsqrtf(s) : 0.f;
}

// ---------------------------------------------------------------------------
// 256x256-tile MX-fp8 GEMM + fused argmax, 32x32x64 MFMA, 128x64 wave tiles.
// Rationale: R0/R1/R2 all pinned at MfmaUtil~25% regardless of schedule or
// occupancy -> LDS-read-bound. FLOP/LDS-byte = 2MN/(M+N) per wave tile:
// 64x32 gave 43; 128x64 gives 85 (2x). 32x32x64 frags also halve ds_read
// instruction count per FLOP. LDS 128 KiB (A,B double-buffered), 8 waves.
// 4 phases per 128B K-tile keyed by mi (A sub-block); B (4 frags) read once
// per tile in P0 and held in regs. A stored with (mi<->wr) row permute so
// stage instr h (64 LDS rows) == phase-h read region:
//   LDS row = mi*64 + wr*32 + r   <->  global row = wr*128 + mi*32 + r
// Staging discipline (as R2): region staged >=1 barrier after last read;
// counted vmcnt(7) gate once per K-tile (never 0 in steady state); raw
// s_barrier; setprio around MFMA cluster; XOR chunk swizzle via source addr.
__global__ __launch_bounds__(512, 2) void gemm_argmax(
        const unsigned char* __restrict__ Sq, const unsigned char* __restrict__ Iq,
        const unsigned short* __restrict__ Sb, const unsigned short* __restrict__ Ib,
        const float* __restrict__ sinv,
        float* __restrict__ pval, int* __restrict__ pidx) {
    const int bid = blockIdx.x;
    const int it = bid % NTILES, jt = bid / NTILES; // consecutive bids share B
    const int i0 = it * 256, j0 = jt * 256;

    __shared__ __align__(16) unsigned char Af[2][256][128];   // 64 KB
    __shared__ __align__(16) unsigned char Bf[2][256][128];   // 64 KB

    const int tid = threadIdx.x;
    const int L = tid & 63, w = tid >> 6;      // 8 waves
    const int wr = w >> 2, wc = w & 3;         // 2x4 wave grid -> 128x64/wave

    f32x16_t acc[4][2];
    #pragma unroll
    for (int a = 0; a < 4; a++)
        #pragma unroll
        for (int b = 0; b < 2; b++)
            acc[a][b] = (f32x16_t){0.f,0.f,0.f,0.f,0.f,0.f,0.f,0.f,
                                   0.f,0.f,0.f,0.f,0.f,0.f,0.f,0.f};

    // Staging: one global_load_lds = 512 thr x 16B = 8 KB = 64 LDS rows.
    // Wave w writes LDS rows 8w..8w+7 (linear dest); chunk swizzle
    // stored[row][c] = global[row][c ^ (row&7)] applied via the source addr
    // (row&7 == L>>3 at the writing lane).
    const int swz = ((L & 7) ^ (L >> 3)) << 4;
    // A: instr h covers LDS rows 64h+.. ; global row = (w>>2)*128 + 32h + 8*(w&3) + (L>>3)
    const unsigned char* pA = Sq + (size_t)(i0 + (w >> 2) * 128 + 8 * (w & 3) + (L >> 3)) * DQ + swz;
    // B: linear; global row = j0 + 64h + 8w + (L>>3)
    const unsigned char* pB = Iq + (size_t)(j0 + 8 * w + (L >> 3)) * DQ + swz;

#define STG_A(h, ko, b) GLOAD_LDS16(pA + (size_t)(32 * (h)) * DQ + (ko), \
                                    &Af[b][((h) << 6) + (w << 3)][0])
#define STG_B(h, ko, b) GLOAD_LDS16(pB + (size_t)(64 * (h)) * DQ + (ko), \
                                    &Bf[b][((h) << 6) + (w << 3)][0])

    // Fragment read: lane L needs bytes [kh*64 + (L>>5)*32, +32) of its row
    // = swizzled 16B chunks (kh*4 + (L>>5)*2 + {0,1}) ^ (L&7).
#define LDFRAG(dst, rowp, kh) {                                               \
    const unsigned char* p_ = (rowp);                                         \
    v4i_t lo_ = *(const v4i_t*)(p_ + (((((kh) << 2) + ((L >> 5) << 1)    ) ^ (L & 7)) << 4)); \
    v4i_t hi_ = *(const v4i_t*)(p_ + (((((kh) << 2) + ((L >> 5) << 1) + 1) ^ (L & 7)) << 4)); \
    dst = __builtin_shufflevector(lo_, hi_, 0, 1, 2, 3, 4, 5, 6, 7); }

#define AROW(b, mi) (&Af[b][((mi) << 6) + (wr << 5) + (L & 31)][0])
#define BROW(b, nj) (&Bf[b][(wc << 6) + ((nj) << 5) + (L & 31)][0])

#define RDB(b) LDFRAG(bq0, BROW(b, 0), 0) LDFRAG(bq1, BROW(b, 1), 0) \
               LDFRAG(bq2, BROW(b, 0), 1) LDFRAG(bq3, BROW(b, 1), 1)

#define MXMFMA(a, b, c) __builtin_amdgcn_mfma_scale_f32_32x32x64_f8f6f4( \
    a, b, c, 0, 0, 0, 0x7F, 0, 0x7F)

#define GATE7 asm volatile("s_waitcnt vmcnt(7)" ::: "memory");
#define GATE4 asm volatile("s_waitcnt vmcnt(4)" ::: "memory");
#define GATE0 asm volatile("s_waitcnt vmcnt(0)" ::: "memory");

// One phase: {ds_read frags || issue stages} -> barrier -> lgkmcnt(0) ->
// setprio(1) MFMA x4 setprio(0) -> [vmcnt gate] -> barrier.
#define PHASE(b, mi, RDB_, STAGES, GATE) {                              \
    v8i_t a0_, a1_;                                                     \
    RDB_                                                                \
    LDFRAG(a0_, AROW(b, mi), 0)                                         \
    LDFRAG(a1_, AROW(b, mi), 1)                                         \
    STAGES                                                              \
    __builtin_amdgcn_sched_barrier(0);                                  \
    __builtin_amdgcn_s_barrier();                                       \
    asm volatile("s_waitcnt lgkmcnt(0)" ::: "memory");                  \
    __builtin_amdgcn_sched_barrier(0);                                  \
    __builtin_amdgcn_s_setprio(1);                                      \
    acc[mi][0] = MXMFMA(a0_, bq0, acc[mi][0]);                          \
    acc[mi][1] = MXMFMA(a0_, bq1, acc[mi][1]);                          \
    acc[mi][0] = MXMFMA(a1_, bq2, acc[mi][0]);                          \
    acc[mi][1] = MXMFMA(a1_, bq3, acc[mi][1]);                          \
    __builtin_amdgcn_s_setprio(0);                                      \
    __builtin_amdgcn_sched_barrier(0);                                  \
    GATE                                                                \
    __builtin_amdgcn_s_barrier();                                       \
}

    v8i_t bq0, bq1, bq2, bq3;

    // Prologue: tile0 full (8 instr) + tile1 all but A h3 (7 instr).
    // Gate vmcnt(7): tile0's 8 landed, tile1's 7 in flight.
    STG_B(0, 0, 0); STG_B(1, 0, 0); STG_B(2, 0, 0); STG_B(3, 0, 0);
    STG_A(0, 0, 0); STG_A(1, 0, 0); STG_A(2, 0, 0); STG_A(3, 0, 0);
    STG_B(0, 128, 1); STG_B(1, 128, 1); STG_B(2, 128, 1); STG_B(3, 128, 1);
    STG_A(0, 128, 1); STG_A(1, 128, 1); STG_A(2, 128, 1);
    GATE7
    __builtin_amdgcn_s_barrier();

    // Main loop: iter p computes tiles v=2p (buf0, P0-P3) and v+1 (buf1).
    // v.P0 stages A(v+1)h3 [last piece of tile v+1]; v.P1-P3 stage tile v+2
    // into buf0 regions freed by the preceding phase; gate vmcnt(7) at v.P3
    // drains exactly through A(v+1)h3. Mirror for v+1 / tile v+3.
    #pragma unroll 1
    for (int p = 0; p < 8; ++p) {
        PHASE(0, 0, RDB(0), STG_A(3, 128, 1);, )
        PHASE(0, 1, ,       STG_B(0, 256, 0); STG_B(1, 256, 0); STG_A(0, 256, 0);, )
        PHASE(0, 2, ,       STG_B(2, 256, 0); STG_B(3, 256, 0); STG_A(1, 256, 0);, )
        PHASE(0, 3, ,       STG_A(2, 256, 0);, GATE7)
        PHASE(1, 0, RDB(1), STG_A(3, 256, 0);, )
        PHASE(1, 1, ,       STG_B(0, 384, 1); STG_B(1, 384, 1); STG_A(0, 384, 1);, )
        PHASE(1, 2, ,       STG_B(2, 384, 1); STG_B(3, 384, 1); STG_A(1, 384, 1);, )
        PHASE(1, 3, ,       STG_A(2, 384, 1);, GATE7)
        pA += 256; pB += 256;
    }

    // Tiles 16 (buf0) / 17 (buf1); bf16 map-dim tail staged into buf0
    // regions as they free up (At -> Af[0] rows 0-127, Bt -> Bf[0] rows 0-127).
    unsigned short (*At)[32] = (unsigned short(*)[32])&Af[0][0][0];
    unsigned short (*Bt)[32] = (unsigned short(*)[32])&Bf[0][0][0];
    // tail stage: 8 KB instr = 128 rows x 64 B; wave w rows 16w..16w+15;
    // swizzle stored[row][c] = global[row][c ^ (row&3)], row&3 == (L>>2)&3.
    const unsigned short* ptA = Sb + (size_t)(i0 + 16 * w + (L >> 2)) * D_PAD
                              + 2304 + (((L & 3) ^ ((L >> 2) & 3)) << 3);
    const unsigned short* ptB = Ib + (size_t)(j0 + 16 * w + (L >> 2)) * D_PAD
                              + 2304 + (((L & 3) ^ ((L >> 2) & 3)) << 3);
#define TSTG_A(h) GLOAD_LDS16(ptA + (size_t)((h) * 128) * D_PAD, &At[((h) << 7) + (w << 4)][0]);
#define TSTG_B(h) GLOAD_LDS16(ptB + (size_t)((h) * 128) * D_PAD, &Bt[((h) << 7) + (w << 4)][0]);

    PHASE(0, 0, RDB(0), STG_A(3, 128, 1);, )          // 16.P0: complete tile 17
    PHASE(0, 1, ,       TSTG_A(0) TSTG_B(0), )        // regions mi0/Bh0 freed
    PHASE(0, 2, ,       TSTG_A(1) TSTG_B(1), )        // regions mi1/Bh1 freed
    PHASE(0, 3, , , GATE4)                            // tile 17 landed
    PHASE(1, 0, RDB(1), , )
    PHASE(1, 1, , , )
    PHASE(1, 2, , , )
    PHASE(1, 3, , , GATE0)                            // tail landed
#undef PHASE
#undef RDB
#undef STG_A
#undef STG_B
#undef TSTG_A
#undef TSTG_B

    {   // bf16 tail (K=32 over the 50x map dims), same f32x16 accumulators.
        // 32x32x16 bf16: lane reads 8 bf16 at k = kt*16 + (L>>5)*8
        // -> 16B chunk (2*kt + (L>>5)) ^ (row&3), row&3 == L&3.
        bf16x8_t bt[2][2];
        #pragma unroll
        for (int kt = 0; kt < 2; kt++)
            #pragma unroll
            for (int nj = 0; nj < 2; nj++) {
                int row = (wc << 6) + (nj << 5) + (L & 31);
                bt[kt][nj] = *(const bf16x8_t*)
                    &Bt[row][((2 * kt + (L >> 5)) ^ (L & 3)) << 3];
            }
        #pragma unroll
        for (int mi = 0; mi < 4; mi++) {
            int row = (wr << 7) + (mi << 5) + (L & 31);
            #pragma unroll
            for (int kt = 0; kt < 2; kt++) {
                bf16x8_t a_ = *(const bf16x8_t*)
                    &At[row][((2 * kt + (L >> 5)) ^ (L & 3)) << 3];
                acc[mi][0] = __builtin_amdgcn_mfma_f32_32x32x16_bf16(
                    a_, bt[kt][0], acc[mi][0], 0, 0, 0);
                acc[mi][1] = __builtin_amdgcn_mfma_f32_32x32x16_bf16(
                    a_, bt[kt][1], acc[mi][1], 0, 0, 0);
            }
        }
    }

    // Epilogue. 32x32 C/D layout: col = lane&31 (j), row = (r&3) + 8*(r>>2)
    // + 4*(lane>>5) (i). Reduce argmax over the 32 j-lanes per half.
    const int jb = j0 + (wc << 6) + (L & 31);
    const float sj0 = sinv[jb], sj1 = sinv[jb + 32];
    #pragma unroll
    for (int mi = 0; mi < 4; mi++) {
        #pragma unroll
        for (int r = 0; r < 16; r++) {
            float best = -INFINITY; int bidx = 0x7fffffff;
            {
                float v = (jb < N_REAL) ? acc[mi][0][r] * sj0 : -INFINITY;
                if (v > best) { best = v; bidx = jb; }
                int j1 = jb + 32;
                v = (j1 < N_REAL) ? acc[mi][1][r] * sj1 : -INFINITY;
                if (v > best) { best = v; bidx = j1; }
            }
            #pragma unroll
            for (int off = 1; off < 32; off <<= 1) {   // within 32-lane half
                float ov = __shfl_xor(best, off);
                int   oi = __shfl_xor(bidx, off);
                if (ov > best || (ov == best && oi < bidx)) { best = ov; bidx = oi; }
            }
            if ((L & 31) == 0) {
                int i = i0 + (wr << 7) + (mi << 5) + ((L >> 5) << 2)
                      + (r & 3) + ((r >> 2) << 3);
                pval[(size_t)jt * NPI + i] = best;
                pidx[(size_t)jt * NPI + i] = bidx;
            }
        }
    }
}

// ---------------------------------------------------------------------------
// Fused merge + loss (reads bf16 matrices -> precision as before).
__global__ __launch_bounds__(256) void loss_kernel(
        const unsigned short* __restrict__ Ib, const unsigned short* __restrict__ Sb,
        const float* __restrict__ pval, const int* __restrict__ pidx,
        double* __restrict__ accum) {
    __shared__ float wsum[4];
    __shared__ int sjn;
    const int n = blockIdx.x;
    if (threadIdx.x < 64) {                    // wave 0: merge 29 partials
        float v = -INFINITY; int id = 0x7fffffff;
        if (threadIdx.x < NTILES) {
            v  = pval[(size_t)threadIdx.x * NPI + n];
            id = pidx[(size_t)threadIdx.x * NPI + n];
        }
        #pragma unroll
        for (int off = 32; off > 0; off >>= 1) {
            float ov = __shfl_xor(v, off);
            int   oi = __shfl_xor(id, off);
            if (ov > v || (ov == v && oi < id)) { v = ov; id = oi; }
        }
        if (threadIdx.x == 0) sjn = id;
    }
    __syncthreads();
    const int jn = sjn;
    const uint4* ip = (const uint4*)(Ib + (size_t)n  * D_PAD);
    const uint4* sp = (const uint4*)(Sb + (size_t)jn * D_PAD);
    float s = 0.f;
    for (int k = threadIdx.x; k < D_PAD / 8; k += 256) {
        uint4 a = ip[k], b = sp[k];
        float d0 = bflo(a.x) - bflo(b.x), d1 = bfhi(a.x) - bfhi(b.x);
        float d2 = bflo(a.y) - bflo(b.y), d3 = bfhi(a.y) - bfhi(b.y);
        float d4 = bflo(a.z) - bflo(b.z), d5 = bfhi(a.z) - bfhi(b.z);
        float d6 = bflo(a.w) - bflo(b.w), d7 = bfhi(a.w) - bfhi(b.w);
        s = fmaf(d0, d0, s); s = fmaf(d1, d1, s);
        s = fmaf(d2, d2, s); s = fmaf(d3, d3, s);
        s = fmaf(d4, d4, s); s = fmaf(d5, d5, s);
        s = fmaf(d6, d6, s); s = fmaf(d7, d7, s);
    }
    #pragma unroll
    for (int off = 32; off > 0; off >>= 1) s += __shfl_xor(s, off);
    int lane = threadIdx.x & 63, wv = threadIdx.x >> 6;
    if (lane == 0) wsum[wv] = s;
    __syncthreads();
    if (threadIdx.x == 0) {
        double t = (double)wsum[0] + (double)wsum[1] + (double)wsum[2] + (double)wsum[3];
        atomicAdd(accum, t);
    }
}

__global__ void finalize(const double* __restrict__ accum, float* __restrict__ out) {
    out[0] = (float)(accum[0] / (double)((long long)D_REAL * N_REAL));
}

// ---------------------------------------------------------------------------
extern "C" void kernel_launch(void* const* d_in, const int* in_sizes, int n_in,
                              void* d_out, int out_size, void* d_ws, size_t ws_size,
                              hipStream_t stream) {
    const float* style_resp = (const float*)d_in[0];
    const float* style_map  = (const float*)d_in[1];
    const float* output_map = (const float*)d_in[2];
    const float* model_resp = (const float*)d_in[3];
    float* out = (float*)d_out;

    unsigned short* Sb = (unsigned short*)d_ws;
    unsigned short* Ib = Sb + (size_t)D_PAD * NPI;
    unsigned char*  Sq = (unsigned char*)(Ib + (size_t)D_PAD * NPI);
    unsigned char*  Iq = Sq + (size_t)DQ * NPI;
    float* sinv    = (float*)(Iq + (size_t)DQ * NPI);
    float* pval    = sinv + NPI;
    int*   pidx    = (int*)(pval + (size_t)NTILES * NPI);
    double* accum  = (double*)(pidx + (size_t)NTILES * NPI);

    // resp tiles: 85*72 = 6120 blocks; map part: ceil(7225*32/256) = 904 blocks
    build_all<<<dim3(6120 + 904, 2), 256, 0, stream>>>(
        style_resp, model_resp, style_map, output_map, Sb, Ib, Sq, Iq);

    col_norms<<<NPI / 4, 256, 0, stream>>>(Sb, sinv, accum);

    gemm_argmax<<<NTILES * NTILES, 512, 0, stream>>>(Sq, Iq, Sb, Ib, sinv, pval, pidx);

    loss_kernel<<<N_REAL, 256, 0, stream>>>(Ib, Sb, pval, pidx, accum);
    finalize<<<1, 1, 0, stream>>>(accum, out);
}

// Round 4
// 425.027 us; speedup vs baseline: 1.3159x; 1.3159x over previous
//
#include <hip/hip_runtime.h>
#include <float.h>
#include <math.h>

// Problem constants
#define D_REAL 2331   // 259 channels * 3*3 patch
#define D_PAD  2336   // bf16 matrix row length
#define DQ     2304   // fp8 matrix row length (resp dims only; 18*128)
#define N_REAL 7225   // 85*85 patches
#define N_PAD  7296   // 57*128
#define JTILES 57
#define ITILES 57
#define STILES 15     // ceil(57/4) supertile grid per dim

typedef __attribute__((ext_vector_type(8))) short bf16x8_t;  // 8 bf16 = 4 VGPRs
typedef __attribute__((ext_vector_type(4))) float f32x4_t;   // 16x16 MFMA C/D
typedef __attribute__((ext_vector_type(8))) int   v8i_t;     // MX A/B operand
typedef __attribute__((ext_vector_type(4))) int   v4i_t;

__device__ __forceinline__ unsigned short f2bf(float x) {
    union { float f; unsigned int u; } v; v.f = x;
    unsigned int r = v.u + 0x7FFFu + ((v.u >> 16) & 1u);   // RNE
    return (unsigned short)(r >> 16);
}
__device__ __forceinline__ float bflo(unsigned int u) {
    union { unsigned int x; float f; } v; v.x = u << 16; return v.f;
}
__device__ __forceinline__ float bfhi(unsigned int u) {
    union { unsigned int x; float f; } v; v.x = u & 0xFFFF0000u; return v.f;
}

#define GLOAD_LDS16(g, l) __builtin_amdgcn_global_load_lds( \
    (const __attribute__((address_space(1))) void*)(g),     \
    (__attribute__((address_space(3))) void*)(l), 16, 0, 0)

// ---------------------------------------------------------------------------
// Fused build: resp part -> bf16 Pb[n][0..2304) AND fp8 Pq[n][0..2304);
// map part -> bf16 Pb[n][2304..2336) only (50 * avgpool4 + zero pad).
__global__ __launch_bounds__(256) void build_all(
        const float* __restrict__ respS, const float* __restrict__ respI,
        const float* __restrict__ mapS,  const float* __restrict__ mapI,
        unsigned short* __restrict__ PbS, unsigned short* __restrict__ PbI,
        unsigned char* __restrict__ PqS, unsigned char* __restrict__ PqI) {
    const int mat = blockIdx.y;
    unsigned short* Pb = mat ? PbI : PbS;
    const int bx = blockIdx.x;
    if (bx < 6120) {
        const float* resp = mat ? respI : respS;
        unsigned char* Pq = mat ? PqI : PqS;
        __shared__ float slab[5 * 768];        // [cc][rr][col], 15 KB max
        const int u  = bx / 72;                // 0..84
        const int d0 = (bx - u * 72) * 32;     // 0..2272
        const int c0 = d0 / 9;
        const int cN = (d0 + 31) / 9 - c0 + 1; // <= 5
        const int total4 = cN * 192;           // float4 count (768/4 per cc)
        // float4 slab load: within each cc the 768 floats are contiguous in
        // resp (3 rows x 256 cols), and 16B-aligned (offset 768u + cc<<16).
        for (int idx = threadIdx.x; idx < total4; idx += 256) {
            int cc = idx / 192;
            int rem = idx - cc * 192;          // float4 index within cc
            *(float4*)&slab[cc * 768 + rem * 4] =
                *(const float4*)&resp[(((size_t)(c0 + cc)) << 16)
                                      + ((size_t)(3 * u) << 8) + rem * 4];
        }
        __syncthreads();
        const int dl16 = threadIdx.x & 15;     // d-pair index
        const int de = d0 + 2 * dl16, dq = de + 1;
        const int ce = de / 9, re = de - ce * 9, pe = re / 3, qe = re - pe * 3;
        const int co = dq / 9, ro = dq - co * 9, po = ro / 3, qo = ro - po * 3;
        const int base_e = (ce - c0) * 768 + pe * 256 + qe;
        const int base_o = (co - c0) * 768 + po * 256 + qo;
        const int v0 = threadIdx.x >> 4;       // 0..15
        for (int v = v0; v < 85; v += 16) {
            float x0 = slab[base_e + 3 * v];
            float x1 = slab[base_o + 3 * v];
            size_t row = (size_t)(u * 85 + v);
            *(unsigned int*)&Pb[row * D_PAD + de] =
                (unsigned int)f2bf(x0) | ((unsigned int)f2bf(x1) << 16);
            int pk = __builtin_amdgcn_cvt_pk_fp8_f32(x0, x1, 0, false);
            *(unsigned short*)&Pq[row * DQ + de] = (unsigned short)pk;
        }
    } else {
        const float* map = mat ? mapI : mapS;
        int t = (bx - 6120) * 256 + threadIdx.x;
        int n = t >> 5, dm = t & 31;
        if (n >= N_REAL) return;
        float val = 0.f;
        if (dm < 27) {
            int u = n / 85, v = n - u * 85;
            int ch = dm / 9, r9 = dm - ch * 9, p = r9 / 3, q = r9 - p * 3;
            const float* mp = map + ((size_t)ch << 20)
                                  + ((size_t)((3 * u + p) * 4) << 10)
                                  + (size_t)((3 * v + q) * 4);
            float s = 0.f;
            #pragma unroll
            for (int a = 0; a < 4; a++)
                #pragma unroll
                for (int b = 0; b < 4; b++) s += mp[a * 1024 + b];
            val = 3.125f * s;                  // 50 * (1/16)
        }
        Pb[(size_t)n * D_PAD + 2304 + dm] = f2bf(val);
    }
}

// ---------------------------------------------------------------------------
// sinv[n] = 1/||S[:,n]|| (bf16 matrix).
__global__ __launch_bounds__(256) void col_norms(const unsigned short* __restrict__ Sb,
                                                 float* __restrict__ sinv) {
    int n = blockIdx.x * 4 + (threadIdx.x >> 6);
    int lane = threadIdx.x & 63;
    const uint4* sp = (const uint4*)(Sb + (size_t)n * D_PAD);
    float s = 0.f;
    for (int k = lane; k < D_PAD / 8; k += 64) {
        uint4 a = sp[k];
        float x0 = bflo(a.x), x1 = bfhi(a.x), x2 = bflo(a.y), x3 = bfhi(a.y);
        float x4 = bflo(a.z), x5 = bfhi(a.z), x6 = bflo(a.w), x7 = bfhi(a.w);
        s = fmaf(x0, x0, s); s = fmaf(x1, x1, s);
        s = fmaf(x2, x2, s); s = fmaf(x3, x3, s);
        s = fmaf(x4, x4, s); s = fmaf(x5, x5, s);
        s = fmaf(x6, x6, s); s = fmaf(x7, x7, s);
    }
    #pragma unroll
    for (int off = 32; off > 0; off >>= 1) s += __shfl_xor(s, off);
    if (lane == 0) sinv[n] = (n < N_REAL) ? rsqrtf(s) : 0.f;
}

// ---------------------------------------------------------------------------
// MX-fp8 GEMM + fused argmax (best-measured R0 structure, 212us).
// K split: 18 x (16x16x128 f8f6f4, unit scales) over the resp dims + 1 x
// (16x16x32 bf16) tail over the 50x-weighted map dims (same f32 acc).
// Double-buffered 16KB fp8 tiles (64KB LDS, one barrier per K-tile), XOR
// chunk swizzle, 4x4 supertile swizzle.
__global__ __launch_bounds__(256) void gemm_argmax(
        const unsigned char* __restrict__ Sq, const unsigned char* __restrict__ Iq,
        const unsigned short* __restrict__ Sb, const unsigned short* __restrict__ Ib,
        const float* __restrict__ sinv,
        float* __restrict__ pval, int* __restrict__ pidx) {
    const int lb = blockIdx.x;
    const int sup = lb >> 4, win = lb & 15;
    const int it4 = (sup / STILES) * 4 + (win & 3);
    const int jt4 = (sup % STILES) * 4 + (win >> 2);
    if (it4 >= ITILES || jt4 >= JTILES) return;   // uniform: no barrier executed
    const int i0 = it4 * 128, j0 = jt4 * 128;

    __shared__ __align__(16) unsigned char Af[2][128][128];   // 32 KB
    __shared__ __align__(16) unsigned char Bf[2][128][128];   // 32 KB
    const int tid = threadIdx.x;
    const int L = tid & 63, w = tid >> 6;
    const int m = L & 15, q = L >> 4;
    const int wi = (w >> 1) * 64, wj = (w & 1) * 64;

    f32x4_t acc[4][4];
    #pragma unroll
    for (int a = 0; a < 4; a++)
        #pragma unroll
        for (int b = 0; b < 4; b++) acc[a][b] = (f32x4_t){0.f, 0.f, 0.f, 0.f};

    // fp8 staging: lane L -> LDS row rl = L>>3 (128B rows), chunk pos L&7;
    // global 16B chunk ck = (L&7) ^ (rl&7)  (XOR involution, spreads banks).
    const int rl = L >> 3;
    const int ck = (L & 7) ^ rl;
    const unsigned char* gqa = Sq + (size_t)(i0 + w * 32 + rl) * DQ + (ck << 4);
    const unsigned char* gqb = Iq + (size_t)(j0 + w * 32 + rl) * DQ + (ck << 4);

    // read-side swizzled 16B-chunk byte offsets (row r: stored = c ^ (r&7); r&7 == m&7)
    const int clo = ((((q << 1))     ^ (m & 7)) << 4);
    const int chi = ((((q << 1) | 1) ^ (m & 7)) << 4);

    // bf16 tail staging, overlaid on buffer-0 regions (8KB each)
    unsigned short (*At)[32] = (unsigned short(*)[32])&Af[0][0][0];
    unsigned short (*Bt)[32] = (unsigned short(*)[32])&Bf[0][0][0];
    const int rl2 = L >> 2;
    const int ck2 = (L & 3) ^ ((rl2 >> 1) & 3);
    const unsigned short* gta = Sb + (size_t)(i0 + w * 32 + rl2) * D_PAD + 2304 + (ck2 << 3);
    const unsigned short* gtb = Ib + (size_t)(j0 + w * 32 + rl2) * D_PAD + 2304 + (ck2 << 3);
    const int cht = (q ^ ((m >> 1) & 3)) << 3;   // tail read chunk (shorts)

#define PREFETCH_Q(buf) {                                     \
    GLOAD_LDS16(gqa,             &Af[buf][w * 32     ][0]);   \
    GLOAD_LDS16(gqa +  8 * DQ,   &Af[buf][w * 32 +  8][0]);   \
    GLOAD_LDS16(gqa + 16 * DQ,   &Af[buf][w * 32 + 16][0]);   \
    GLOAD_LDS16(gqa + 24 * DQ,   &Af[buf][w * 32 + 24][0]);   \
    GLOAD_LDS16(gqb,             &Bf[buf][w * 32     ][0]);   \
    GLOAD_LDS16(gqb +  8 * DQ,   &Bf[buf][w * 32 +  8][0]);   \
    GLOAD_LDS16(gqb + 16 * DQ,   &Bf[buf][w * 32 + 16][0]);   \
    GLOAD_LDS16(gqb + 24 * DQ,   &Bf[buf][w * 32 + 24][0]);   \
    gqa += 128; gqb += 128; }

#define COMPUTE_Q(buf) {                                                   \
    v8i_t aq[4], bq[4];                                                    \
    _Pragma("unroll")                                                      \
    for (int mi = 0; mi < 4; mi++) {                                       \
        v4i_t lo = *(const v4i_t*)&Af[buf][wi + mi * 16 + m][clo];         \
        v4i_t hi = *(const v4i_t*)&Af[buf][wi + mi * 16 + m][chi];         \
        aq[mi] = __builtin_shufflevector(lo, hi, 0, 1, 2, 3, 4, 5, 6, 7);  \
    }                                                                      \
    _Pragma("unroll")                                                      \
    for (int nj = 0; nj < 4; nj++) {                                       \
        v4i_t lo = *(const v4i_t*)&Bf[buf][wj + nj * 16 + m][clo];         \
        v4i_t hi = *(const v4i_t*)&Bf[buf][wj + nj * 16 + m][chi];         \
        bq[nj] = __builtin_shufflevector(lo, hi, 0, 1, 2, 3, 4, 5, 6, 7);  \
    }                                                                      \
    _Pragma("unroll")                                                      \
    for (int mi = 0; mi < 4; mi++)                                         \
        _Pragma("unroll")                                                  \
        for (int nj = 0; nj < 4; nj++)                                     \
            acc[mi][nj] = __builtin_amdgcn_mfma_scale_f32_16x16x128_f8f6f4(\
                aq[mi], bq[nj], acc[mi][nj], 0, 0, 0, 0x7F, 0, 0x7F); }

    PREFETCH_Q(0)                              // fp8 tile 0 -> buf 0
    for (int p = 0; p < 8; p++) {              // fp8 tiles 0..15
        __syncthreads();
        PREFETCH_Q(1)
        __builtin_amdgcn_sched_barrier(0);
        COMPUTE_Q(0)
        __syncthreads();
        PREFETCH_Q(0)
        __builtin_amdgcn_sched_barrier(0);
        COMPUTE_Q(1)
    }
    __syncthreads();
    PREFETCH_Q(1)                              // fp8 tile 17
    __builtin_amdgcn_sched_barrier(0);
    COMPUTE_Q(0)                               // fp8 tile 16
    __syncthreads();
    {                                          // bf16 map-dim tail -> buf0 overlay
        GLOAD_LDS16(gta,                      &At[w * 32][0]);
        GLOAD_LDS16(gta + (size_t)16 * D_PAD, &At[w * 32 + 16][0]);
        GLOAD_LDS16(gtb,                      &Bt[w * 32][0]);
        GLOAD_LDS16(gtb + (size_t)16 * D_PAD, &Bt[w * 32 + 16][0]);
    }
    __builtin_amdgcn_sched_barrier(0);
    COMPUTE_Q(1)                               // fp8 tile 17
    __syncthreads();                           // tail tiles ready
    {
        bf16x8_t af[4], bfr[4];
        #pragma unroll
        for (int mi = 0; mi < 4; mi++)
            af[mi] = *(const bf16x8_t*)&At[wi + mi * 16 + m][cht];
        #pragma unroll
        for (int nj = 0; nj < 4; nj++)
            bfr[nj] = *(const bf16x8_t*)&Bt[wj + nj * 16 + m][cht];
        #pragma unroll
        for (int mi = 0; mi < 4; mi++)
            #pragma unroll
            for (int nj = 0; nj < 4; nj++)
                acc[mi][nj] = __builtin_amdgcn_mfma_f32_16x16x32_bf16(
                    af[mi], bfr[nj], acc[mi][nj], 0, 0, 0);
    }
#undef PREFETCH_Q
#undef COMPUTE_Q

    // Epilogue. C/D layout: col = m (j-dir), row = q*4 + reg (i-dir).
    float sjv[4];
    #pragma unroll
    for (int nj = 0; nj < 4; nj++) sjv[nj] = sinv[j0 + wj + nj * 16 + m];
    #pragma unroll
    for (int mi = 0; mi < 4; mi++) {
        #pragma unroll
        for (int r = 0; r < 4; r++) {
            float best = -INFINITY; int bidx = 0x7fffffff;
            #pragma unroll
            for (int nj = 0; nj < 4; nj++) {   // j ascending -> '>' keeps smallest
                int j = j0 + wj + nj * 16 + m;
                float v = (j < N_REAL) ? acc[mi][nj][r] * sjv[nj] : -INFINITY;
                if (v > best) { best = v; bidx = j; }
            }
            #pragma unroll
            for (int off = 1; off < 16; off <<= 1) {
                float ov = __shfl_xor(best, off);
                int   oi = __shfl_xor(bidx, off);
                if (ov > best || (ov == best && oi < bidx)) { best = ov; bidx = oi; }
            }
            if (m == 0) {
                int i = i0 + wi + mi * 16 + q * 4 + r;
                pval[(size_t)jt4 * N_PAD + i] = best;
                pidx[(size_t)jt4 * N_PAD + i] = bidx;
            }
        }
    }
}

// ---------------------------------------------------------------------------
// Fused merge + loss. Writes a per-row partial (NO same-address atomic:
// 7225 device-scope f64 atomicAdds to one address serialize with cross-XCD
// cacheline ping-pong -- Guideline 12).
__global__ __launch_bounds__(256) void loss_kernel(
        const unsigned short* __restrict__ Ib, const unsigned short* __restrict__ Sb,
        const float* __restrict__ pval, const int* __restrict__ pidx,
        double* __restrict__ partial) {
    __shared__ float wsum[4];
    __shared__ int sjn;
    const int n = blockIdx.x;
    if (threadIdx.x < 64) {                    // wave 0: merge 57 partials
        float v = -INFINITY; int id = 0x7fffffff;
        if (threadIdx.x < JTILES) {
            v  = pval[(size_t)threadIdx.x * N_PAD + n];
            id = pidx[(size_t)threadIdx.x * N_PAD + n];
        }
        #pragma unroll
        for (int off = 32; off > 0; off >>= 1) {
            float ov = __shfl_xor(v, off);
            int   oi = __shfl_xor(id, off);
            if (ov > v || (ov == v && oi < id)) { v = ov; id = oi; }
        }
        if (threadIdx.x == 0) sjn = id;
    }
    __syncthreads();
    const int jn = sjn;
    const uint4* ip = (const uint4*)(Ib + (size_t)n  * D_PAD);
    const uint4* sp = (const uint4*)(Sb + (size_t)jn * D_PAD);
    float s = 0.f;
    for (int k = threadIdx.x; k < D_PAD / 8; k += 256) {
        uint4 a = ip[k], b = sp[k];
        float d0 = bflo(a.x) - bflo(b.x), d1 = bfhi(a.x) - bfhi(b.x);
        float d2 = bflo(a.y) - bflo(b.y), d3 = bfhi(a.y) - bfhi(b.y);
        float d4 = bflo(a.z) - bflo(b.z), d5 = bfhi(a.z) - bfhi(b.z);
        float d6 = bflo(a.w) - bflo(b.w), d7 = bfhi(a.w) - bfhi(b.w);
        s = fmaf(d0, d0, s); s = fmaf(d1, d1, s);
        s = fmaf(d2, d2, s); s = fmaf(d3, d3, s);
        s = fmaf(d4, d4, s); s = fmaf(d5, d5, s);
        s = fmaf(d6, d6, s); s = fmaf(d7, d7, s);
    }
    #pragma unroll
    for (int off = 32; off > 0; off >>= 1) s += __shfl_xor(s, off);
    int lane = threadIdx.x & 63, wv = threadIdx.x >> 6;
    if (lane == 0) wsum[wv] = s;
    __syncthreads();
    if (threadIdx.x == 0) {
        partial[n] = (double)wsum[0] + (double)wsum[1]
                   + (double)wsum[2] + (double)wsum[3];
    }
}

// One-block tree reduction of the 7225 per-row partials.
__global__ __launch_bounds__(256) void finalize(const double* __restrict__ partial,
                                                float* __restrict__ out) {
    __shared__ double ws[4];
    double s = 0.0;
    for (int i = threadIdx.x; i < N_REAL; i += 256) s += partial[i];
    #pragma unroll
    for (int off = 32; off > 0; off >>= 1) s += __shfl_xor(s, off);
    int lane = threadIdx.x & 63, wv = threadIdx.x >> 6;
    if (lane == 0) ws[wv] = s;
    __syncthreads();
    if (threadIdx.x == 0) {
        double t = ws[0] + ws[1] + ws[2] + ws[3];
        out[0] = (float)(t / (double)((long long)D_REAL * N_REAL));
    }
}

// ---------------------------------------------------------------------------
extern "C" void kernel_launch(void* const* d_in, const int* in_sizes, int n_in,
                              void* d_out, int out_size, void* d_ws, size_t ws_size,
                              hipStream_t stream) {
    const float* style_resp = (const float*)d_in[0];
    const float* style_map  = (const float*)d_in[1];
    const float* output_map = (const float*)d_in[2];
    const float* model_resp = (const float*)d_in[3];
    float* out = (float*)d_out;

    unsigned short* Sb = (unsigned short*)d_ws;
    unsigned short* Ib = Sb + (size_t)D_PAD * N_PAD;
    unsigned char*  Sq = (unsigned char*)(Ib + (size_t)D_PAD * N_PAD);
    unsigned char*  Iq = Sq + (size_t)DQ * N_PAD;
    float* sinv     = (float*)(Iq + (size_t)DQ * N_PAD);
    float* pval     = sinv + N_PAD;
    int*   pidx     = (int*)(pval + (size_t)JTILES * N_PAD);
    double* partial = (double*)(pidx + (size_t)JTILES * N_PAD);

    // resp tiles: 85*72 = 6120 blocks; map part: ceil(7225*32/256) = 904 blocks
    build_all<<<dim3(6120 + 904, 2), 256, 0, stream>>>(
        style_resp, model_resp, style_map, output_map, Sb, Ib, Sq, Iq);

    col_norms<<<N_PAD / 4, 256, 0, stream>>>(Sb, sinv);

    gemm_argmax<<<STILES * STILES * 16, 256, 0, stream>>>(Sq, Iq, Sb, Ib, sinv, pval, pidx);

    loss_kernel<<<N_REAL, 256, 0, stream>>>(Ib, Sb, pval, pidx, partial);
    finalize<<<1, 256, 0, stream>>>(partial, out);
}